// Round 6
// baseline (186.902 us; speedup 1.0000x reference)
//
#include <hip/hip_runtime.h>
#include <math.h>

#define LOG2E 1.4426950408889634f
#define LN2 0.6931471805599453f

constexpr int B_ = 16;
constexpr int T_ = 512;
constexpr int E_ = 512;    // K of GEMM
constexpr int V_ = 5000;   // true N
constexpr int VP_ = 5120;  // padded N (multiple of 128)
constexpr int CB_ = VP_ / 128;  // 40 col-blocks
constexpr int L_ = 64;
constexpr int S_ = 2 * L_ + 1;  // 129
constexpr int SP_ = 132;        // padded emit/lraw stride (16B-aligned rows)
constexpr int CLDS_STRIDE = 132;  // Clds row stride in ushorts

typedef __attribute__((ext_vector_type(8))) short bf16x8;
typedef __attribute__((ext_vector_type(4))) float f32x4;

#define GLOAD_LDS16(g, l)                                                              \
  __builtin_amdgcn_global_load_lds((const __attribute__((address_space(1))) void*)(g), \
                                   (__attribute__((address_space(3))) void*)(l), 16, 0, 0)

__device__ __forceinline__ unsigned short f2bf(float x) {
  unsigned int u = __float_as_uint(x);
  unsigned int r = (u + 0x7fffu + ((u >> 16) & 1u)) >> 16;  // RNE
  return (unsigned short)r;
}
__device__ __forceinline__ float bf2f(unsigned int lo16) {
  return __uint_as_float(lo16 << 16);
}

__device__ __forceinline__ float hexp2(float x) { return __builtin_amdgcn_exp2f(x); }
__device__ __forceinline__ float hlog2(float x) { return __builtin_amdgcn_logf(x); }

// neighbor a1 from lane-1 via DPP: row_shr:1 with row_bcast15 patch; lane0 -> 0
__device__ __forceinline__ float dpp_shr1_zero(float v) {
  int s = __float_as_int(v);
  int bc = __builtin_amdgcn_update_dpp(0, s, 0x142, 0xF, 0xF, false);   // row_bcast15
  int r = __builtin_amdgcn_update_dpp(bc, s, 0x111, 0xF, 0xF, false);   // row_shr:1
  return __int_as_float(r);
}

template <int CTRL>
__device__ __forceinline__ float dpp_mv(float v) {
  int s = __float_as_int(v);
  return __int_as_float(__builtin_amdgcn_update_dpp(s, s, CTRL, 0xF, 0xF, false));
}

// ---------- block reduction helper (256 threads = 4 waves) ----------
__device__ __forceinline__ float blockReduceF(float v, bool is_max, volatile float* red) {
  int tid = threadIdx.x, lane = tid & 63, wid = tid >> 6;
#pragma unroll
  for (int off = 32; off > 0; off >>= 1) {
    float o = __shfl_down(v, off, 64);
    v = is_max ? fmaxf(v, o) : (v + o);
  }
  __syncthreads();
  if (lane == 0) red[wid] = v;
  __syncthreads();
  float r = red[0];
#pragma unroll
  for (int w = 1; w < 4; ++w) r = is_max ? fmaxf(r, (float)red[w]) : (r + (float)red[w]);
  return r;
}

// ---------- conversion: hs_pad f32 -> bf16 ----------
__global__ __launch_bounds__(256) void convA(const float* __restrict__ X,
                                             unsigned short* __restrict__ Y, int n4) {
  int i = blockIdx.x * 256 + threadIdx.x;
  if (i >= n4) return;
  float4 v = ((const float4*)X)[i];
  ushort4 o;
  o.x = f2bf(v.x); o.y = f2bf(v.y); o.z = f2bf(v.z); o.w = f2bf(v.w);
  ((ushort4*)Y)[i] = o;
}

// ---------- conversion: W [512][5000] f32 -> W_T [5120][512] bf16 ----------
__global__ __launch_bounds__(256) void convW(const float* __restrict__ W,
                                             unsigned short* __restrict__ Wt) {
  __shared__ float tile[32][33];
  int n0 = blockIdx.x * 32, k0 = blockIdx.y * 32;
  int tid = threadIdx.x;
  int tx = tid & 31, ty = tid >> 5;
#pragma unroll
  for (int p = 0; p < 4; ++p) {
    int k = k0 + ty + p * 8, n = n0 + tx;
    tile[ty + p * 8][tx] = (n < V_) ? W[(size_t)k * V_ + n] : 0.0f;
  }
  __syncthreads();
#pragma unroll
  for (int p = 0; p < 4; ++p) {
    int n = n0 + ty + p * 8, k = k0 + tx;
    Wt[(size_t)n * E_ + k] = f2bf(tile[tx][ty + p * 8]);
  }
}

// ---------- Kernel A: fused bf16 MFMA GEMM + per-row split-V softmax partials ----------
// No C written to HBM. Per block: partial (suml, sums, dot) per row -> part[row][cb][3];
// CTC label logits owned by this block's columns -> lraw[row][s].
__global__ __launch_bounds__(256) void gemm_fused(const unsigned short* __restrict__ A,
                                                  const unsigned short* __restrict__ Wt,
                                                  const float* __restrict__ bias,
                                                  const float* __restrict__ soft,
                                                  const int* __restrict__ targets,
                                                  float* __restrict__ part,
                                                  float* __restrict__ lraw) {
  __shared__ __align__(16) char smem[128 * CLDS_STRIDE * 2];  // 33792 B
  __shared__ int tgt[64];
  unsigned short* As = (unsigned short*)smem;              // 128*32 (dead after k-loop)
  unsigned short* Bs = As + 128 * 32;                      // 128*32
  unsigned short* Clds = (unsigned short*)smem;            // 128*132, overlays As/Bs

  int tid = threadIdx.x;
  int l = tid & 63, wid = tid >> 6;
  int lane15 = l & 15, lhalf = l >> 4;
  int wr = wid >> 1, wc = wid & 1;
  int bn = blockIdx.x * 128;
  int bm = blockIdx.y * 128;
  int bidx = bm >> 9;  // / T_ (128 | 512 so one batch per block)
  if (tid < 64) tgt[tid] = targets[bidx * L_ + tid];

  f32x4 acc[4][4] = {};

  int srow = l >> 2;
  int scol = (l & 3) * 8;
  for (int k0 = 0; k0 < E_; k0 += 32) {
#pragma unroll
    for (int i = 0; i < 2; ++i) {
      int rb = wid * 32 + i * 16;
      GLOAD_LDS16(A + (size_t)(bm + rb + srow) * E_ + k0 + scol, &As[rb * 32]);
      GLOAD_LDS16(Wt + (size_t)(bn + rb + srow) * E_ + k0 + scol, &Bs[rb * 32]);
    }
    __syncthreads();
    bf16x8 af[4], bf[4];
#pragma unroll
    for (int m = 0; m < 4; ++m)
      af[m] = *(const bf16x8*)&As[(wr * 64 + m * 16 + lane15) * 32 + lhalf * 8];
#pragma unroll
    for (int n = 0; n < 4; ++n)
      bf[n] = *(const bf16x8*)&Bs[(wc * 64 + n * 16 + lane15) * 32 + lhalf * 8];
#pragma unroll
    for (int m = 0; m < 4; ++m)
#pragma unroll
      for (int n = 0; n < 4; ++n)
        acc[m][n] = __builtin_amdgcn_mfma_f32_16x16x32_bf16(af[m], bf[n], acc[m][n], 0, 0, 0);
    __syncthreads();
  }

  // ---- epilogue: C tile (+bias) -> LDS bf16 (overlays As/Bs, now dead) ----
#pragma unroll
  for (int n = 0; n < 4; ++n) {
    int cl = wc * 64 + n * 16 + lane15;
    int col = bn + cl;
    float bv = (col < V_) ? bias[col] : 0.0f;
#pragma unroll
    for (int m = 0; m < 4; ++m) {
      int r0 = wr * 64 + m * 16 + lhalf * 4;
#pragma unroll
      for (int j = 0; j < 4; ++j)
        Clds[(r0 + j) * CLDS_STRIDE + cl] = f2bf(acc[m][n][j] + bv);
    }
  }
  __syncthreads();

  // ---- stream soft subtile, compute per-row partials (2 threads per row) ----
  int r = tid >> 1, ch = tid & 1;  // row r, column half ch (64 cols)
  const float* srp = soft + (size_t)(bm + r) * V_ + bn + ch * 64;
  const unsigned short* clr = Clds + r * CLDS_STRIDE + ch * 64;
  float pl = 0.f, ps = 0.f, pd = 0.f;
  if (bn + 128 <= V_) {
#pragma unroll 4
    for (int i = 0; i < 16; ++i) {
      float4 sv = *(const float4*)(srp + i * 4);
      ushort4 lv = *(const ushort4*)(clr + i * 4);
      float l0 = bf2f(lv.x), l1 = bf2f(lv.y), l2 = bf2f(lv.z), l3 = bf2f(lv.w);
      pl += hexp2(l0 * LOG2E) + hexp2(l1 * LOG2E) + hexp2(l2 * LOG2E) + hexp2(l3 * LOG2E);
      float e0 = hexp2(sv.x * LOG2E), e1 = hexp2(sv.y * LOG2E);
      float e2 = hexp2(sv.z * LOG2E), e3 = hexp2(sv.w * LOG2E);
      ps += (e0 + e1) + (e2 + e3);
      pd = fmaf(e0, l0, fmaf(e1, l1, fmaf(e2, l2, fmaf(e3, l3, pd))));
    }
  } else {
    // last col-block: only cols < V_ participate
    for (int i = 0; i < 64; ++i) {
      int col = bn + ch * 64 + i;
      if (col < V_) {
        float s = srp[i];
        float lv = bf2f(clr[i]);
        pl += hexp2(lv * LOG2E);
        float e = hexp2(s * LOG2E);
        ps += e;
        pd = fmaf(e, lv, pd);
      }
    }
  }
  // pair-combine (lanes 2r, 2r+1 are adjacent in the same wave)
  pl += __shfl_xor(pl, 1, 64);
  ps += __shfl_xor(ps, 1, 64);
  pd += __shfl_xor(pd, 1, 64);
  if (ch == 0) {
    float* pp = part + ((size_t)(bm + r) * CB_ + blockIdx.x) * 3;
    pp[0] = pl; pp[1] = ps; pp[2] = pd;
  }

  // ---- scatter CTC label logits owned by this block's columns ----
  if (tid < 128) {
    int row = tid;
    const unsigned short* cr = Clds + row * CLDS_STRIDE;
    float* lr = lraw + (size_t)(bm + row) * SP_;
#pragma unroll 1
    for (int s = 0; s < S_; ++s) {
      int c = (s & 1) ? tgt[s >> 1] : 0;  // blank = 0
      int cc = c - bn;
      if (cc >= 0 && cc < 128) lr[s] = bf2f(cr[cc]);
    }
  }
}

// ---------- Kernel B: finalize rows (sum partials -> lse/cxe; scaled emissions) ----------
__global__ __launch_bounds__(256) void finalize(const float* __restrict__ part,
                                                const float* __restrict__ lraw,
                                                const int* __restrict__ hlens,
                                                float* __restrict__ cxe,
                                                float* __restrict__ emit) {
  int row = blockIdx.x * 4 + (threadIdx.x >> 6);
  int l = threadIdx.x & 63;
  int bidx = row >> 9, t = row & (T_ - 1);
  const float* pp = part + (size_t)row * CB_ * 3;
  float sl = 0.f, ss = 0.f, sd = 0.f;
  if (l < CB_) { sl = pp[l * 3]; ss = pp[l * 3 + 1]; sd = pp[l * 3 + 2]; }
#pragma unroll
  for (int off = 32; off > 0; off >>= 1) {
    sl += __shfl_xor(sl, off, 64);
    ss += __shfl_xor(ss, off, 64);
    sd += __shfl_xor(sd, off, 64);
  }
  float lse = hlog2(sl) * LN2;
  if (l == 0) cxe[row] = (t < hlens[bidx]) ? (lse - sd / ss) : 0.0f;

  const float* lr = lraw + (size_t)row * SP_;
  float e0 = (lr[l] - lse) * LOG2E;
  float e1 = (lr[l + 64] - lse) * LOG2E;
  float e2 = (l == 0) ? (lr[128] - lse) * LOG2E : -3e38f;
  float m = fmaxf(fmaxf(e0, e1), e2);
#pragma unroll
  for (int off = 32; off > 0; off >>= 1) m = fmaxf(m, __shfl_xor(m, off, 64));
  float* er = emit + (size_t)row * SP_;
  er[l] = hexp2(e0 - m);
  er[l + 64] = hexp2(e1 - m);
  if (l == 0) {
    er[128] = hexp2(e2 - m);
    er[130] = m;  // K_t
  }
}

// ---------- Kernel C: CTC forward, prob domain, DPP neighbor, renorm every 8 ----------
__device__ __forceinline__ void pstep(float& a0, float& a1, float& a2, float allowf,
                                      float e0, float e1, float e2) {
  float ua1 = dpp_shr1_zero(a1);
  float n0 = (a0 + ua1) * e0;
  float n1 = fmaf(ua1, allowf, a0 + a1) * e1;
  float n2 = (a2 + a1) * e2;
  a0 = n0; a1 = n1; a2 = n2;
}

__device__ __forceinline__ void renorm(float& a0, float& a1, float& a2, float& shift,
                                       int lane) {
  float m = fmaxf(a0, a1);
  m = (lane == 63) ? fmaxf(m, a2) : m;
  m = fmaxf(m, dpp_mv<0xB1>(m));
  m = fmaxf(m, dpp_mv<0x4E>(m));
  m = fmaxf(m, dpp_mv<0x124>(m));
  m = fmaxf(m, dpp_mv<0x128>(m));
  m = fmaxf(m, __shfl_xor(m, 16, 64));
  m = fmaxf(m, __shfl_xor(m, 32, 64));
  m = fmaxf(m, 1e-35f);
  float rs = __builtin_amdgcn_rcpf(m) * 281474976710656.0f;  // *2^48 headroom
  a0 *= rs; a1 *= rs; a2 *= rs;
  shift -= hlog2(rs);
}

__global__ __launch_bounds__(64) void ctc_fwd(const float* __restrict__ emit,
                                              const int* __restrict__ hlens,
                                              const int* __restrict__ targets,
                                              const int* __restrict__ olens,
                                              float* __restrict__ ctc_out) {
  int b = blockIdx.x;
  int l = threadIdx.x;
  const float* Eb = emit + (size_t)b * T_ * SP_;
  float allowf = 0.f;
  if (l >= 1) allowf = (targets[b * L_ + l] != targets[b * L_ + l - 1]) ? 1.0f : 0.0f;

  float a0, a1, a2, shift;
  {
    float2 e01 = *(const float2*)(Eb + 2 * l);
    float4 x = *(const float4*)(Eb + 128);
    a0 = (l == 0) ? e01.x : 0.0f;
    a1 = (l == 0) ? e01.y : 0.0f;
    a2 = 0.0f;
    shift = x.z;  // K_0
  }
  int ilen = hlens[b];

#define LDE(tt) (*(const float2*)(Eb + (size_t)(tt) * SP_ + 2 * l))
#define LDX(tt) (*(const float4*)(Eb + (size_t)(tt) * SP_ + 128))

  float2 c0 = LDE(1), c1 = LDE(2), c2 = LDE(3), c3 = LDE(4);
  float2 c4 = LDE(5), c5 = LDE(6), c6 = LDE(7), c7 = LDE(8);
  float4 x0 = LDX(1), x1 = LDX(2), x2 = LDX(3), x3 = LDX(4);
  float4 x4 = LDX(5), x5 = LDX(6), x6 = LDX(7), x7 = LDX(8);

  int t = 1;
  for (; t + 7 <= ilen - 1; t += 8) {
    float2 p0 = LDE(t + 8), p1 = LDE(t + 9), p2 = LDE(t + 10), p3 = LDE(t + 11);
    float2 p4 = LDE(t + 12), p5 = LDE(t + 13), p6 = LDE(t + 14), p7 = LDE(t + 15);
    float4 q0 = LDX(t + 8), q1 = LDX(t + 9), q2 = LDX(t + 10), q3 = LDX(t + 11);
    float4 q4 = LDX(t + 12), q5 = LDX(t + 13), q6 = LDX(t + 14), q7 = LDX(t + 15);
    pstep(a0, a1, a2, allowf, c0.x, c0.y, x0.x);
    pstep(a0, a1, a2, allowf, c1.x, c1.y, x1.x);
    pstep(a0, a1, a2, allowf, c2.x, c2.y, x2.x);
    pstep(a0, a1, a2, allowf, c3.x, c3.y, x3.x);
    pstep(a0, a1, a2, allowf, c4.x, c4.y, x4.x);
    pstep(a0, a1, a2, allowf, c5.x, c5.y, x5.x);
    pstep(a0, a1, a2, allowf, c6.x, c6.y, x6.x);
    pstep(a0, a1, a2, allowf, c7.x, c7.y, x7.x);
    shift += ((x0.z + x1.z) + (x2.z + x3.z)) + ((x4.z + x5.z) + (x6.z + x7.z));
    renorm(a0, a1, a2, shift, l);
    c0 = p0; c1 = p1; c2 = p2; c3 = p3; c4 = p4; c5 = p5; c6 = p6; c7 = p7;
    x0 = q0; x1 = q1; x2 = q2; x3 = q3; x4 = q4; x5 = q5; x6 = q6; x7 = q7;
  }
  int rem = ilen - t;
  if (rem > 0) { pstep(a0, a1, a2, allowf, c0.x, c0.y, x0.x); shift += x0.z; }
  if (rem > 1) { pstep(a0, a1, a2, allowf, c1.x, c1.y, x1.x); shift += x1.z; }
  if (rem > 2) { pstep(a0, a1, a2, allowf, c2.x, c2.y, x2.x); shift += x2.z; }
  if (rem > 3) { pstep(a0, a1, a2, allowf, c3.x, c3.y, x3.x); shift += x3.z; }
  if (rem > 4) { pstep(a0, a1, a2, allowf, c4.x, c4.y, x4.x); shift += x4.z; }
  if (rem > 5) { pstep(a0, a1, a2, allowf, c5.x, c5.y, x5.x); shift += x5.z; }
  if (rem > 6) { pstep(a0, a1, a2, allowf, c6.x, c6.y, x6.x); shift += x6.z; }
#undef LDE
#undef LDX

  int end = 2 * olens[b];  // 64..128, even
  float aE = (end == 128) ? __shfl(a2, 63, 64) : __shfl(a0, end >> 1, 64);
  float aE1 = __shfl(a1, (end >> 1) - 1, 64);
  if (l == 0) {
    float p = aE + aE1;
    float ll = (hlog2(p) + shift) * LN2;
    float loss = -ll;
    if (!(loss <= 1e20f)) loss = 0.0f;  // zero_infinity (catches inf/nan too)
    ctc_out[b] = loss;
  }
}

// ---------- Kernel D: final combine ----------
__global__ __launch_bounds__(256) void final_reduce(const float* __restrict__ cxe,
                                                    const float* __restrict__ ctco,
                                                    float* __restrict__ out) {
  __shared__ float red[4];
  float s = 0.f;
  for (int i = threadIdx.x; i < B_ * T_; i += 256) s += cxe[i];
  s = blockReduceF(s, false, red);
  if (threadIdx.x == 0) {
    float c = 0.f;
    for (int b = 0; b < B_; ++b) c += ctco[b];
    out[0] = 0.5f * (s / (float)B_) + 0.5f * (c / (float)B_);
  }
}

extern "C" void kernel_launch(void* const* d_in, const int* in_sizes, int n_in,
                              void* d_out, int out_size, void* d_ws, size_t ws_size,
                              hipStream_t stream) {
  const float* hs = (const float*)d_in[0];
  const float* soft = (const float*)d_in[1];
  const float* W = (const float*)d_in[2];
  const float* bias = (const float*)d_in[3];
  const int* hlens = (const int*)d_in[4];
  const int* targets = (const int*)d_in[5];
  const int* olens = (const int*)d_in[6];
  float* out = (float*)d_out;

  int total = B_ * T_;  // 8192 rows
  size_t emit_n = (size_t)(total + 16) * SP_;  // +16 rows slack for ctc prefetch
  float* emit = (float*)d_ws;
  float* cxe = emit + emit_n;
  float* ctco = cxe + (size_t)total;
  unsigned short* Abf = (unsigned short*)(ctco + 16);       // 8192*512 bf16
  unsigned short* Wt = Abf + (size_t)total * E_;            // 5120*512 bf16
  float* lraw = (float*)(Wt + (size_t)VP_ * E_);            // 8192*132 f32
  float* part = lraw + (size_t)total * SP_;                 // 8192*40*3 f32

  dim3 blk(256);
  {
    int n4 = total * E_ / 4;
    hipLaunchKernelGGL(convA, dim3((n4 + 255) / 256), blk, 0, stream, hs, Abf, n4);
    hipLaunchKernelGGL(convW, dim3(VP_ / 32, E_ / 32), blk, 0, stream, W, Wt);
  }

  hipLaunchKernelGGL(gemm_fused, dim3(CB_, total / 128), blk, 0, stream, Abf, Wt, bias,
                     soft, targets, part, lraw);
  hipLaunchKernelGGL(finalize, dim3(total / 4), blk, 0, stream, part, lraw, hlens, cxe, emit);
  hipLaunchKernelGGL(ctc_fwd, dim3(B_), dim3(64), 0, stream, emit, hlens, targets, olens, ctco);
  hipLaunchKernelGGL(final_reduce, dim3(1), blk, 0, stream, cxe, ctco, out);
}